// Round 14
// baseline (93.762 us; speedup 1.0000x reference)
//
#include <hip/hip_runtime.h>

// CategorySpecificLinear: out[t] = x[t] @ W[cid[t]] + bias[cid[t]]
// Pipeline (2 dispatches):
//   k_prep: block 0 = bucketize; [1,tpw] = W transpose->bf16; cvt x->bf16; zero out.
//   k_ggemm: m97-faithful grouped GEMM: 256 thr (4 waves 2x2, 64x64/wave,
//            acc 4x4, 32 MFMA/iter), BM=BN=128, BK=64, single 32KB LDS buffer,
//            __syncthreads drain, SPLIT-K=4 -> 4 blocks/CU; atomicAdd epilogue
//            (L2-local: all kz of a tile share an XCD via blockIdx.x=c).

typedef __attribute__((ext_vector_type(8))) short bf16x8;
typedef __attribute__((ext_vector_type(4))) float f32x4;
typedef __attribute__((ext_vector_type(8))) unsigned short ushort8_t;

__device__ __forceinline__ unsigned short f2bf(float f) {
  unsigned u = __float_as_uint(f);
  u += 0x7FFFu + ((u >> 16) & 1u);   // round-to-nearest-even
  return (unsigned short)(u >> 16);
}

// async global->LDS, 16B per lane; LDS dest = wave-uniform base + lane*16
__device__ __forceinline__ void gload_lds16(const unsigned short* g, unsigned short* l) {
  __builtin_amdgcn_global_load_lds(
      (const __attribute__((address_space(1))) unsigned int*)g,
      (__attribute__((address_space(3))) unsigned int*)l, 16, 0, 0);
}

#define MAXC 8

// ---- kernel 1: fused prep (unchanged from R13) ----
__global__ void k_prep(const float* __restrict__ W, unsigned short* __restrict__ Wt,
                       int Dd, int Oo,
                       const float* __restrict__ x, unsigned short* __restrict__ xb, int nX,
                       const int* __restrict__ cid, int* __restrict__ counts,
                       int* __restrict__ bucket, int T, int C, int tpw, int cvtb,
                       float* __restrict__ outZ, int nOut) {
  int b   = blockIdx.x;
  int tid = threadIdx.x;

  if (b == 0) {
    __shared__ int cnt[256][MAXC];
    int tpt = (T + 255) / 256;
    int t0  = tid * tpt;
    int t1  = min(t0 + tpt, T);
    for (int c = 0; c < C; ++c) cnt[tid][c] = 0;
    for (int t = t0; t < t1; ++t) cnt[tid][cid[t]]++;
    __syncthreads();
    if (tid < C) {
      int run = 0;
      for (int t = 0; t < 256; ++t) { int v = cnt[t][tid]; cnt[t][tid] = run; run += v; }
      counts[tid] = run;
    }
    __syncthreads();
    for (int t = t0; t < t1; ++t) {
      int c = cid[t];
      int p = cnt[tid][c]++;
      bucket[c * T + p] = t;
    }
    return;
  }

  if (b > tpw + cvtb) {  // zero-out role
    int i = ((b - tpw - cvtb - 1) * 256 + tid) * 8;
    if (i >= nOut) return;
    float4 z = {0.f, 0.f, 0.f, 0.f};
    *reinterpret_cast<float4*>(outZ + i)     = z;
    *reinterpret_cast<float4*>(outZ + i + 4) = z;
    return;
  }

  if (b > tpw) {  // cvt role
    int i = ((b - tpw - 1) * 256 + tid) * 8;
    if (i >= nX) return;
    float4 a0 = *reinterpret_cast<const float4*>(x + i);
    float4 a1 = *reinterpret_cast<const float4*>(x + i + 4);
    ushort8_t o;
    o[0] = f2bf(a0.x); o[1] = f2bf(a0.y); o[2] = f2bf(a0.z); o[3] = f2bf(a0.w);
    o[4] = f2bf(a1.x); o[5] = f2bf(a1.y); o[6] = f2bf(a1.z); o[7] = f2bf(a1.w);
    *reinterpret_cast<ushort8_t*>(xb + i) = o;
    return;
  }

  // transpose role
  int bb  = b - 1;
  int tpc = (Dd / 64) * (Oo / 64);
  int c   = bb / tpc;
  int rem = bb % tpc;
  int d0  = (rem / (Oo / 64)) * 64;
  int o0  = (rem % (Oo / 64)) * 64;

  __shared__ float t[64][65];
  const float* Wc = W + (size_t)c * Dd * Oo;
#pragma unroll
  for (int p = 0; p < 4; ++p) {
    int chunk = p * 256 + tid;
    int r  = chunk >> 4;
    int cb = chunk & 15;
    float4 v = *reinterpret_cast<const float4*>(Wc + (size_t)(d0 + r) * Oo + o0 + cb * 4);
    t[r][cb * 4 + 0] = v.x; t[r][cb * 4 + 1] = v.y;
    t[r][cb * 4 + 2] = v.z; t[r][cb * 4 + 3] = v.w;
  }
  __syncthreads();
  unsigned short* Wtc = Wt + (size_t)c * Oo * Dd;
#pragma unroll
  for (int p = 0; p < 2; ++p) {
    int chunk = p * 256 + tid;
    int orow = chunk >> 3;
    int dseg = chunk & 7;
    ushort8_t w;
#pragma unroll
    for (int j = 0; j < 8; ++j) w[j] = f2bf(t[dseg * 8 + j][orow]);
    *reinterpret_cast<ushort8_t*>(Wtc + (size_t)(o0 + orow) * Dd + d0 + dseg * 8) = w;
  }
}

// ---- kernel 2: grouped GEMM, m97 structure + split-K=4 ----
#define BM 128
#define BN 128
#define BK 64
#define KSPLIT 4
#define TILE_SH (BM * BK)   // 8192 elems = 16KB per operand

__global__ __launch_bounds__(256, 4) void k_ggemm(
    const unsigned short* __restrict__ xb, const unsigned short* __restrict__ Wt,
    const float* __restrict__ bias, const int* __restrict__ counts,
    const int* __restrict__ bucket, float* __restrict__ out,
    int T, int Dd, int Oo) {
  int c  = blockIdx.x;
  int Mc = counts[c];
  int kz = blockIdx.z & (KSPLIT - 1);
  int m0 = (blockIdx.z >> 2) * BM;
  if (m0 >= Mc) return;  // block-uniform exit
  int n0 = blockIdx.y * BN;

  __shared__ __align__(16) unsigned short Al[TILE_SH];  // 16KB
  __shared__ __align__(16) unsigned short Bl[TILE_SH];  // 16KB -> 32KB, 4 blk/CU

  const int tid  = threadIdx.x;
  const int lane = tid & 63;
  const int wid  = tid >> 6;                 // 0..3
  const int wm   = wid >> 1, wn = wid & 1;   // 2x2 waves, each 64x64 of C

  const int* buck = bucket + c * T;
  const unsigned short* Wc = Wt + (size_t)c * Oo * Dd;
  const int kbase = kz * (Dd / KSPLIT);      // 256-elem K-range per split

  // staging (m97-style): per wave 4 A-gloads + 4 B-gloads per K-iter; load i
  // covers rows [wid*32 + i*8, +8). Linear LDS dest; global source seg
  // pre-swizzled (seg = (lane&7) ^ (row&7)). [rule 21; proven R1-R13]
  const unsigned short* aSrc[4];
  const unsigned short* bSrc[4];
  int sOff[4];  // wave-uniform
#pragma unroll
  for (int i = 0; i < 4; ++i) {
    int row = wid * 32 + i * 8 + (lane >> 3);
    int seg = (lane & 7) ^ (row & 7);
    int mr  = m0 + row;
    int tok = buck[mr < Mc ? mr : Mc - 1];  // clamp; masked at epilogue
    aSrc[i] = xb + (size_t)tok * Dd + kbase + seg * 8;
    bSrc[i] = Wc + (size_t)(n0 + row) * Dd + kbase + seg * 8;
    sOff[i] = (wid * 32 + i * 8) * BK;
  }

  const f32x4 fzero = {0.f, 0.f, 0.f, 0.f};
  f32x4 acc[4][4];
#pragma unroll
  for (int i = 0; i < 4; ++i)
#pragma unroll
    for (int j = 0; j < 4; ++j) acc[i][j] = fzero;

  const int KT = Dd / BK / KSPLIT;  // 4

  for (int kt = 0; kt < KT; ++kt) {
    int ko = kt * BK;
    // stage tile kt (single buffer, m97 pattern)
#pragma unroll
    for (int i = 0; i < 4; ++i) {
      gload_lds16(aSrc[i] + ko, Al + sOff[i]);
      gload_lds16(bSrc[i] + ko, Bl + sOff[i]);
    }
    __syncthreads();  // drains vmcnt(0) lgkmcnt(0): tile landed, all waves ready

    // compute tile kt: 2 kk-slabs x 16 MFMA (m97's 32 MFMA/iter/wave)
#pragma unroll
    for (int kk = 0; kk < 2; ++kk) {
      bf16x8 af[4], bf[4];
#pragma unroll
      for (int mi = 0; mi < 4; ++mi) {
        int row  = wm * 64 + mi * 16 + (lane & 15);
        int slot = (kk * 4 + (lane >> 4)) ^ (row & 7);
        af[mi] = *reinterpret_cast<const bf16x8*>(&Al[row * BK + slot * 8]);
      }
#pragma unroll
      for (int ni = 0; ni < 4; ++ni) {
        int row  = wn * 64 + ni * 16 + (lane & 15);
        int slot = (kk * 4 + (lane >> 4)) ^ (row & 7);
        bf[ni] = *reinterpret_cast<const bf16x8*>(&Bl[row * BK + slot * 8]);
      }
#pragma unroll
      for (int mi = 0; mi < 4; ++mi)
#pragma unroll
        for (int ni = 0; ni < 4; ++ni)
          acc[mi][ni] = __builtin_amdgcn_mfma_f32_16x16x32_bf16(af[mi], bf[ni], acc[mi][ni], 0, 0, 0);
    }
    if (kt + 1 < KT) __syncthreads();  // all waves' frag reads done before restage
  }

  // epilogue: atomicAdd partials (out zeroed in k_prep); kz==0 adds bias.
  // Deterministic: fp32 + is exact-commutative over any arrival order w/ base 0.
#pragma unroll
  for (int mi = 0; mi < 4; ++mi) {
    int rb = m0 + wm * 64 + mi * 16 + (lane >> 4) * 4;
#pragma unroll
    for (int r = 0; r < 4; ++r) {
      int mrow = rb + r;
      if (mrow < Mc) {
        int tok = buck[mrow];
        float* orow = out + (size_t)tok * Oo;
#pragma unroll
        for (int ni = 0; ni < 4; ++ni) {
          int col = n0 + wn * 64 + ni * 16 + (lane & 15);
          float v = acc[mi][ni][r] + (kz == 0 ? bias[c * Oo + col] : 0.f);
          atomicAdd(&orow[col], v);
        }
      }
    }
  }
}

extern "C" void kernel_launch(void* const* d_in, const int* in_sizes, int n_in,
                              void* d_out, int out_size, void* d_ws, size_t ws_size,
                              hipStream_t stream) {
  const float* x    = (const float*)d_in[0];
  const int*   cid  = (const int*)d_in[1];
  const float* W    = (const float*)d_in[2];
  const float* bias = (const float*)d_in[3];
  float* out = (float*)d_out;

  int T = in_sizes[1];            // 4096
  int D = in_sizes[0] / T;        // 1024
  int O = out_size / T;           // 1024
  int C = in_sizes[3] / O;        // 8

  char* ws = (char*)d_ws;
  int* counts = (int*)ws;                                   // C ints
  int* bucket = (int*)(ws + 64);                            // C*T ints
  unsigned short* xb = (unsigned short*)(ws + 64 + (size_t)C * T * 4);  // T*D bf16
  unsigned short* Wt = xb + (size_t)T * D;                  // C*O*D bf16

  int tpw  = C * (D / 64) * (O / 64);            // 2048 transpose blocks
  int cvtb = (T * D / 8 + 255) / 256;            // 2048 cvt blocks
  int zb   = (out_size / 8 + 255) / 256;         // 2048 zero-out blocks
  k_prep<<<1 + tpw + cvtb + zb, 256, 0, stream>>>(W, Wt, D, O, x, xb, T * D,
                                                  cid, counts, bucket, T, C, tpw, cvtb,
                                                  out, out_size);
  k_ggemm<<<dim3(C, O / BN, KSPLIT * ((T + BM - 1) / BM)), 256, 0, stream>>>(
      xb, Wt, bias, counts, bucket, out, T, D, O);
}

// Round 15
// 75.541 us; speedup vs baseline: 1.2412x; 1.2412x over previous
//
#include <hip/hip_runtime.h>

// CategorySpecificLinear: out[t] = x[t] @ W[cid[t]] + bias[cid[t]]
// Pipeline (2 dispatches):
//   k_prep: block 0 = deterministic bucketize; [1,tpw] = W transpose->bf16;
//           rest = x cvt->bf16.
//   k_ggemm: LDS-FREE direct-register GEMM. Both operands are k-major, so each
//     MFMA fragment is one per-lane global_load_dwordx4 (16B contiguous k).
//     No barriers, no LDS: waves independent; L1 (32KB/CU) provides intra-block
//     reuse (per-K-step working set 16KB), L2 serves ~200MB @ 36.9 TB/s.
//     256 thr = 2x2 waves of 64x64; depth-1 register pipeline (named sets).

typedef __attribute__((ext_vector_type(8))) short bf16x8;
typedef __attribute__((ext_vector_type(4))) float f32x4;
typedef __attribute__((ext_vector_type(8))) unsigned short ushort8_t;

__device__ __forceinline__ unsigned short f2bf(float f) {
  unsigned u = __float_as_uint(f);
  u += 0x7FFFu + ((u >> 16) & 1u);   // round-to-nearest-even
  return (unsigned short)(u >> 16);
}

#define MAXC 8

// ---- kernel 1: fused prep (R11 version: bucketize + transpose + cvt) ----
__global__ void k_prep(const float* __restrict__ W, unsigned short* __restrict__ Wt,
                       int Dd, int Oo,
                       const float* __restrict__ x, unsigned short* __restrict__ xb, int nX,
                       const int* __restrict__ cid, int* __restrict__ counts,
                       int* __restrict__ bucket, int T, int C, int tpw) {
  int b   = blockIdx.x;
  int tid = threadIdx.x;

  if (b == 0) {
    __shared__ int cnt[256][MAXC];
    int tpt = (T + 255) / 256;
    int t0  = tid * tpt;
    int t1  = min(t0 + tpt, T);
    for (int c = 0; c < C; ++c) cnt[tid][c] = 0;
    for (int t = t0; t < t1; ++t) cnt[tid][cid[t]]++;
    __syncthreads();
    if (tid < C) {
      int run = 0;
      for (int t = 0; t < 256; ++t) { int v = cnt[t][tid]; cnt[t][tid] = run; run += v; }
      counts[tid] = run;
    }
    __syncthreads();
    for (int t = t0; t < t1; ++t) {
      int c = cid[t];
      int p = cnt[tid][c]++;
      bucket[c * T + p] = t;
    }
    return;
  }

  if (b > tpw) {  // cvt role: x fp32 -> bf16, 8/thread
    int i = ((b - tpw - 1) * 256 + tid) * 8;
    if (i >= nX) return;
    float4 a0 = *reinterpret_cast<const float4*>(x + i);
    float4 a1 = *reinterpret_cast<const float4*>(x + i + 4);
    ushort8_t o;
    o[0] = f2bf(a0.x); o[1] = f2bf(a0.y); o[2] = f2bf(a0.z); o[3] = f2bf(a0.w);
    o[4] = f2bf(a1.x); o[5] = f2bf(a1.y); o[6] = f2bf(a1.z); o[7] = f2bf(a1.w);
    *reinterpret_cast<ushort8_t*>(xb + i) = o;
    return;
  }

  // transpose role: 64x64 tile of W[c]
  int bb  = b - 1;
  int tpc = (Dd / 64) * (Oo / 64);
  int c   = bb / tpc;
  int rem = bb % tpc;
  int d0  = (rem / (Oo / 64)) * 64;
  int o0  = (rem % (Oo / 64)) * 64;

  __shared__ float t[64][65];
  const float* Wc = W + (size_t)c * Dd * Oo;
#pragma unroll
  for (int p = 0; p < 4; ++p) {
    int chunk = p * 256 + tid;
    int r  = chunk >> 4;
    int cb = chunk & 15;
    float4 v = *reinterpret_cast<const float4*>(Wc + (size_t)(d0 + r) * Oo + o0 + cb * 4);
    t[r][cb * 4 + 0] = v.x; t[r][cb * 4 + 1] = v.y;
    t[r][cb * 4 + 2] = v.z; t[r][cb * 4 + 3] = v.w;
  }
  __syncthreads();
  unsigned short* Wtc = Wt + (size_t)c * Oo * Dd;
#pragma unroll
  for (int p = 0; p < 2; ++p) {
    int chunk = p * 256 + tid;
    int orow = chunk >> 3;
    int dseg = chunk & 7;
    ushort8_t w;
#pragma unroll
    for (int j = 0; j < 8; ++j) w[j] = f2bf(t[dseg * 8 + j][orow]);
    *reinterpret_cast<ushort8_t*>(Wtc + (size_t)(o0 + orow) * Dd + d0 + dseg * 8) = w;
  }
}

// ---- kernel 2: LDS-free grouped GEMM ----
#define BM 128
#define BN 128

__global__ __launch_bounds__(256) void k_ggemm(
    const unsigned short* __restrict__ xb, const unsigned short* __restrict__ Wt,
    const float* __restrict__ bias, const int* __restrict__ counts,
    const int* __restrict__ bucket, float* __restrict__ out,
    int T, int Dd, int Oo) {
  int c  = blockIdx.x;
  int Mc = counts[c];
  int m0 = blockIdx.z * BM;
  if (m0 >= Mc) return;  // block-uniform exit (most z-slices dead; cheap)
  int n0 = blockIdx.y * BN;

  const int tid  = threadIdx.x;
  const int lane = tid & 63;
  const int wid  = tid >> 6;                 // 0..3
  const int wm   = wid >> 1, wn = wid & 1;   // 2x2 waves, each 64x64 of C

  const int* buck = bucket + c * T;
  const unsigned short* Wc = Wt + (size_t)c * Oo * Dd;
  const int kg = (lane >> 4) * 8;            // this lane's k-group offset (elems)

  // per-lane fragment base addresses (16B-contiguous in k)
  const unsigned short* aBase[4];
  const unsigned short* bBase[4];
#pragma unroll
  for (int mi = 0; mi < 4; ++mi) {
    int mrow = m0 + wm * 64 + mi * 16 + (lane & 15);
    int tok  = buck[mrow < Mc ? mrow : Mc - 1];  // clamp; masked at epilogue
    aBase[mi] = xb + (size_t)tok * Dd + kg;
  }
#pragma unroll
  for (int ni = 0; ni < 4; ++ni) {
    int col = n0 + wn * 64 + ni * 16 + (lane & 15);
    bBase[ni] = Wc + (size_t)col * Dd + kg;
  }

  const f32x4 fzero = {0.f, 0.f, 0.f, 0.f};
  f32x4 acc[4][4];
#pragma unroll
  for (int i = 0; i < 4; ++i)
#pragma unroll
    for (int j = 0; j < 4; ++j) acc[i][j] = fzero;

  // two named fragment sets (rule #20: static indexing only)
  bf16x8 Fa0[4], Fb0[4], Fa1[4], Fb1[4];

#define LOADF(SA, SB, kt) do {                                                \
    _Pragma("unroll")                                                         \
    for (int i_ = 0; i_ < 4; ++i_) {                                          \
      SA[i_] = *reinterpret_cast<const bf16x8*>(aBase[i_] + (kt) * 32);       \
      SB[i_] = *reinterpret_cast<const bf16x8*>(bBase[i_] + (kt) * 32);       \
    } } while (0)
#define MMF(SA, SB) do {                                                      \
    _Pragma("unroll")                                                         \
    for (int mi_ = 0; mi_ < 4; ++mi_)                                         \
      _Pragma("unroll")                                                       \
      for (int ni_ = 0; ni_ < 4; ++ni_)                                       \
        acc[mi_][ni_] = __builtin_amdgcn_mfma_f32_16x16x32_bf16(              \
            SA[mi_], SB[ni_], acc[mi_][ni_], 0, 0, 0);                        \
    } while (0)

  const int KT = Dd / 32;  // 32 K-steps of 32
  LOADF(Fa0, Fb0, 0);
  for (int kt = 0; kt < KT; kt += 2) {
    LOADF(Fa1, Fb1, kt + 1);      // prefetch next while computing current
    MMF(Fa0, Fb0);
    if (kt + 2 < KT) LOADF(Fa0, Fb0, kt + 2);
    MMF(Fa1, Fb1);
  }
#undef LOADF
#undef MMF

  // epilogue: D layout col=lane&15, row=(lane>>4)*4+r  [m89-verified]
#pragma unroll
  for (int mi = 0; mi < 4; ++mi) {
    int rb = m0 + wm * 64 + mi * 16 + (lane >> 4) * 4;
#pragma unroll
    for (int r = 0; r < 4; ++r) {
      int mrow = rb + r;
      if (mrow < Mc) {
        int tok = buck[mrow];
        float* orow = out + (size_t)tok * Oo;
#pragma unroll
        for (int ni = 0; ni < 4; ++ni) {
          int col = n0 + wn * 64 + ni * 16 + (lane & 15);
          orow[col] = acc[mi][ni][r] + bias[c * Oo + col];
        }
      }
    }
  }
}

extern "C" void kernel_launch(void* const* d_in, const int* in_sizes, int n_in,
                              void* d_out, int out_size, void* d_ws, size_t ws_size,
                              hipStream_t stream) {
  const float* x    = (const float*)d_in[0];
  const int*   cid  = (const int*)d_in[1];
  const float* W    = (const float*)d_in[2];
  const float* bias = (const float*)d_in[3];
  float* out = (float*)d_out;

  int T = in_sizes[1];            // 4096
  int D = in_sizes[0] / T;        // 1024
  int O = out_size / T;           // 1024
  int C = in_sizes[3] / O;        // 8

  char* ws = (char*)d_ws;
  int* counts = (int*)ws;                                   // C ints
  int* bucket = (int*)(ws + 64);                            // C*T ints
  unsigned short* xb = (unsigned short*)(ws + 64 + (size_t)C * T * 4);  // T*D bf16
  unsigned short* Wt = xb + (size_t)T * D;                  // C*O*D bf16

  int tpw  = C * (D / 64) * (O / 64);            // 2048 transpose blocks
  int cvtb = (T * D / 8 + 255) / 256;            // 2048 cvt blocks
  k_prep<<<1 + tpw + cvtb, 256, 0, stream>>>(W, Wt, D, O, x, xb, T * D,
                                             cid, counts, bucket, T, C, tpw);
  k_ggemm<<<dim3(C, O / BN, (T + BM - 1) / BM), 256, 0, stream>>>(
      xb, Wt, bias, counts, bucket, out, T, D, O);
}

// Round 16
// 70.479 us; speedup vs baseline: 1.3304x; 1.0718x over previous
//
#include <hip/hip_runtime.h>

// CategorySpecificLinear: out[t] = x[t] @ W[cid[t]] + bias[cid[t]]
// Pipeline (2 dispatches):
//   k_prep: block 0 = deterministic bucketize; [1,tpw] = W transpose->bf16;
//           rest = x cvt->bf16.  (unchanged, R15 version)
//   k_ggemm: R11 base (BM=BN=128, BK=64, 1024thr = 16 waves 4x4, cat->XCD) with
//     A-PATH MOVED OFF LDS: A-frags are direct per-lane 16B register loads
//     (prefetched, compiler-waited); B stays gload_lds depth-3 counted (1
//     inst/wave/iter, 48KB LDS). Halves per-block gload_lds count — the
//     empirical per-iteration cost driver (R8/R9/R11 fit).

typedef __attribute__((ext_vector_type(8))) short bf16x8;
typedef __attribute__((ext_vector_type(4))) float f32x4;
typedef __attribute__((ext_vector_type(8))) unsigned short ushort8_t;

__device__ __forceinline__ unsigned short f2bf(float f) {
  unsigned u = __float_as_uint(f);
  u += 0x7FFFu + ((u >> 16) & 1u);   // round-to-nearest-even
  return (unsigned short)(u >> 16);
}

// async global->LDS, 16B per lane; LDS dest = wave-uniform base + lane*16
__device__ __forceinline__ void gload_lds16(const unsigned short* g, unsigned short* l) {
  __builtin_amdgcn_global_load_lds(
      (const __attribute__((address_space(1))) unsigned int*)g,
      (__attribute__((address_space(3))) unsigned int*)l, 16, 0, 0);
}

#define MAXC 8

// ---- kernel 1: fused prep (unchanged from R15) ----
__global__ void k_prep(const float* __restrict__ W, unsigned short* __restrict__ Wt,
                       int Dd, int Oo,
                       const float* __restrict__ x, unsigned short* __restrict__ xb, int nX,
                       const int* __restrict__ cid, int* __restrict__ counts,
                       int* __restrict__ bucket, int T, int C, int tpw) {
  int b   = blockIdx.x;
  int tid = threadIdx.x;

  if (b == 0) {
    __shared__ int cnt[256][MAXC];
    int tpt = (T + 255) / 256;
    int t0  = tid * tpt;
    int t1  = min(t0 + tpt, T);
    for (int c = 0; c < C; ++c) cnt[tid][c] = 0;
    for (int t = t0; t < t1; ++t) cnt[tid][cid[t]]++;
    __syncthreads();
    if (tid < C) {
      int run = 0;
      for (int t = 0; t < 256; ++t) { int v = cnt[t][tid]; cnt[t][tid] = run; run += v; }
      counts[tid] = run;
    }
    __syncthreads();
    for (int t = t0; t < t1; ++t) {
      int c = cid[t];
      int p = cnt[tid][c]++;
      bucket[c * T + p] = t;
    }
    return;
  }

  if (b > tpw) {  // cvt role: x fp32 -> bf16, 8/thread
    int i = ((b - tpw - 1) * 256 + tid) * 8;
    if (i >= nX) return;
    float4 a0 = *reinterpret_cast<const float4*>(x + i);
    float4 a1 = *reinterpret_cast<const float4*>(x + i + 4);
    ushort8_t o;
    o[0] = f2bf(a0.x); o[1] = f2bf(a0.y); o[2] = f2bf(a0.z); o[3] = f2bf(a0.w);
    o[4] = f2bf(a1.x); o[5] = f2bf(a1.y); o[6] = f2bf(a1.z); o[7] = f2bf(a1.w);
    *reinterpret_cast<ushort8_t*>(xb + i) = o;
    return;
  }

  // transpose role: 64x64 tile of W[c]
  int bb  = b - 1;
  int tpc = (Dd / 64) * (Oo / 64);
  int c   = bb / tpc;
  int rem = bb % tpc;
  int d0  = (rem / (Oo / 64)) * 64;
  int o0  = (rem % (Oo / 64)) * 64;

  __shared__ float t[64][65];
  const float* Wc = W + (size_t)c * Dd * Oo;
#pragma unroll
  for (int p = 0; p < 4; ++p) {
    int chunk = p * 256 + tid;
    int r  = chunk >> 4;
    int cb = chunk & 15;
    float4 v = *reinterpret_cast<const float4*>(Wc + (size_t)(d0 + r) * Oo + o0 + cb * 4);
    t[r][cb * 4 + 0] = v.x; t[r][cb * 4 + 1] = v.y;
    t[r][cb * 4 + 2] = v.z; t[r][cb * 4 + 3] = v.w;
  }
  __syncthreads();
  unsigned short* Wtc = Wt + (size_t)c * Oo * Dd;
#pragma unroll
  for (int p = 0; p < 2; ++p) {
    int chunk = p * 256 + tid;
    int orow = chunk >> 3;
    int dseg = chunk & 7;
    ushort8_t w;
#pragma unroll
    for (int j = 0; j < 8; ++j) w[j] = f2bf(t[dseg * 8 + j][orow]);
    *reinterpret_cast<ushort8_t*>(Wtc + (size_t)(o0 + orow) * Dd + d0 + dseg * 8) = w;
  }
}

// ---- kernel 2: grouped GEMM — A direct-to-reg, B gload_lds depth-3 ----
#define BM 128
#define BN 128
#define BK 64
#define TILE_B (BN * BK)   // 8192 elems = 16KB

__global__ __launch_bounds__(1024) void k_ggemm(
    const unsigned short* __restrict__ xb, const unsigned short* __restrict__ Wt,
    const float* __restrict__ bias, const int* __restrict__ counts,
    const int* __restrict__ bucket, float* __restrict__ out,
    int T, int Dd, int Oo) {
  int c  = blockIdx.x;
  int Mc = counts[c];
  int m0 = blockIdx.z * BM;
  if (m0 >= Mc) return;  // block-uniform exit
  int n0 = blockIdx.y * BN;

  __shared__ __align__(16) unsigned short Bl[3][TILE_B];  // 48KB

  const int tid  = threadIdx.x;
  const int lane = tid & 63;
  const int wid  = tid >> 6;                 // 0..15
  const int wm   = wid >> 2, wn = wid & 3;   // 4x4 waves, each 32x32 of C

  const int* buck = bucket + c * T;
  const unsigned short* Wc = Wt + (size_t)c * Oo * Dd;

  // B staging: 1 gload_lds/wave/iter; wave w covers rows [w*8, w*8+8).
  // Linear LDS dest; source seg pre-swizzled (seg = (lane&7) ^ (row&7)). [rule 21]
  const unsigned short* bSrc;
  int bOff;
  {
    int row = wid * 8 + (lane >> 3);
    int seg = (lane & 7) ^ (row & 7);
    bSrc = Wc + (size_t)(n0 + row) * Dd + seg * 8;
    bOff = (wid * 8) * BK;
  }

  // A direct: per-lane frag bases (16B contiguous in k). [R15-verified layout]
  const unsigned short* aB[2];
#pragma unroll
  for (int mi = 0; mi < 2; ++mi) {
    int mrow = m0 + wm * 32 + mi * 16 + (lane & 15);
    int tok  = buck[mrow < Mc ? mrow : Mc - 1];  // clamp; masked at epilogue
    aB[mi] = xb + (size_t)tok * Dd + (lane >> 4) * 8;
  }

  const f32x4 fzero = {0.f, 0.f, 0.f, 0.f};
  f32x4 acc[2][2];
#pragma unroll
  for (int i = 0; i < 2; ++i)
#pragma unroll
    for (int j = 0; j < 2; ++j) acc[i][j] = fzero;

  const int KT = Dd / BK;  // 16

  // prologue: B(0), B(1) in flight; A(kt=0,kk=0) into regs
  gload_lds16(bSrc,      Bl[0] + bOff);
  gload_lds16(bSrc + BK, Bl[1] + bOff);
  bf16x8 a0[2], a1[2];
  a0[0] = *reinterpret_cast<const bf16x8*>(aB[0]);
  a0[1] = *reinterpret_cast<const bf16x8*>(aB[1]);

  for (int kt = 0; kt < KT; ++kt) {
    int cur = kt % 3;
    int ko  = kt * BK;
    // seam: all waves' Bl-frag reads of prev iter drained (lgkm), B(kt) landed
    // per-wave via the A-consume vmcnt chain; vmcnt(2) tolerates the 2 newer
    // in-flight ops (next-B / next-A pair).
    asm volatile("s_waitcnt lgkmcnt(0)" ::: "memory");
    if (kt < KT - 1) {
      asm volatile("s_waitcnt vmcnt(2)" ::: "memory");
    } else {
      asm volatile("s_waitcnt vmcnt(0)" ::: "memory");
    }
    __builtin_amdgcn_sched_barrier(0);
    __builtin_amdgcn_s_barrier();
    __builtin_amdgcn_sched_barrier(0);

    // A kk=1 frags for this iter (issued first: stays older than B(kt+2))
    a1[0] = *reinterpret_cast<const bf16x8*>(aB[0] + ko + 32);
    a1[1] = *reinterpret_cast<const bf16x8*>(aB[1] + ko + 32);
    // B(kt+2) into Bl[(kt+2)%3] — its readers drained at this seam
    if (kt + 2 < KT) {
      int nb = (kt + 2) % 3;
      gload_lds16(bSrc + (kt + 2) * BK, Bl[nb] + bOff);
    }

    // kk = 0 (uses preloaded a0)
    {
      bf16x8 bf[2];
#pragma unroll
      for (int ni = 0; ni < 2; ++ni) {
        int row  = wn * 32 + ni * 16 + (lane & 15);
        int slot = (lane >> 4) ^ (row & 7);
        bf[ni] = *reinterpret_cast<const bf16x8*>(&Bl[cur][row * BK + slot * 8]);
      }
#pragma unroll
      for (int mi = 0; mi < 2; ++mi)
#pragma unroll
        for (int ni = 0; ni < 2; ++ni)
          acc[mi][ni] = __builtin_amdgcn_mfma_f32_16x16x32_bf16(a0[mi], bf[ni], acc[mi][ni], 0, 0, 0);
    }
    // reload a0 for next iter (crosses the next barrier in flight; newest op)
    if (kt + 1 < KT) {
      a0[0] = *reinterpret_cast<const bf16x8*>(aB[0] + ko + BK);
      a0[1] = *reinterpret_cast<const bf16x8*>(aB[1] + ko + BK);
    }
    // kk = 1
    {
      bf16x8 bf[2];
#pragma unroll
      for (int ni = 0; ni < 2; ++ni) {
        int row  = wn * 32 + ni * 16 + (lane & 15);
        int slot = (4 + (lane >> 4)) ^ (row & 7);
        bf[ni] = *reinterpret_cast<const bf16x8*>(&Bl[cur][row * BK + slot * 8]);
      }
#pragma unroll
      for (int mi = 0; mi < 2; ++mi)
#pragma unroll
        for (int ni = 0; ni < 2; ++ni)
          acc[mi][ni] = __builtin_amdgcn_mfma_f32_16x16x32_bf16(a1[mi], bf[ni], acc[mi][ni], 0, 0, 0);
    }
  }

  // epilogue: D layout col=lane&15, row=(lane>>4)*4+r  [m89-verified]
#pragma unroll
  for (int mi = 0; mi < 2; ++mi) {
    int rb = m0 + wm * 32 + mi * 16 + (lane >> 4) * 4;
#pragma unroll
    for (int r = 0; r < 4; ++r) {
      int mrow = rb + r;
      if (mrow < Mc) {
        int tok = buck[mrow];
        float* orow = out + (size_t)tok * Oo;
#pragma unroll
        for (int ni = 0; ni < 2; ++ni) {
          int col = n0 + wn * 32 + ni * 16 + (lane & 15);
          orow[col] = acc[mi][ni][r] + bias[c * Oo + col];
        }
      }
    }
  }
}

extern "C" void kernel_launch(void* const* d_in, const int* in_sizes, int n_in,
                              void* d_out, int out_size, void* d_ws, size_t ws_size,
                              hipStream_t stream) {
  const float* x    = (const float*)d_in[0];
  const int*   cid  = (const int*)d_in[1];
  const float* W    = (const float*)d_in[2];
  const float* bias = (const float*)d_in[3];
  float* out = (float*)d_out;

  int T = in_sizes[1];            // 4096
  int D = in_sizes[0] / T;        // 1024
  int O = out_size / T;           // 1024
  int C = in_sizes[3] / O;        // 8

  char* ws = (char*)d_ws;
  int* counts = (int*)ws;                                   // C ints
  int* bucket = (int*)(ws + 64);                            // C*T ints
  unsigned short* xb = (unsigned short*)(ws + 64 + (size_t)C * T * 4);  // T*D bf16
  unsigned short* Wt = xb + (size_t)T * D;                  // C*O*D bf16

  int tpw  = C * (D / 64) * (O / 64);            // 2048 transpose blocks
  int cvtb = (T * D / 8 + 255) / 256;            // 2048 cvt blocks
  k_prep<<<1 + tpw + cvtb, 256, 0, stream>>>(W, Wt, D, O, x, xb, T * D,
                                             cid, counts, bucket, T, C, tpw);
  k_ggemm<<<dim3(C, O / BN, (T + BM - 1) / BM), 1024, 0, stream>>>(
      xb, Wt, bias, counts, bucket, out, T, D, O);
}

// Round 17
// 48.473 us; speedup vs baseline: 1.9343x; 1.4540x over previous
//
#include <hip/hip_runtime.h>

// CategorySpecificLinear: out[t] = x[t] @ W[cid[t]] + bias[cid[t]]
// Pipeline (2 dispatches):
//   k_prep: block 0 = deterministic bucketize; [1,tpw] = W transpose->bf16;
//           rest = x cvt->bf16.
//   k_ggemm: R11 champion (BM=BN=128, BK=64, 1024 thr = 16 waves 4x4,
//     depth-3 counted vmcnt(2), 96KB LDS, cat->XCD) + PHASE-SPLIT K-step:
//     {A-gload | frags kk0 | prio MFMA} barrier {B-gload | frags kk1 | prio MFMA}.
//     m196/m218b: phase-split + setprio is the measured lever at 1 blk/CU.

typedef __attribute__((ext_vector_type(8))) short bf16x8;
typedef __attribute__((ext_vector_type(4))) float f32x4;
typedef __attribute__((ext_vector_type(8))) unsigned short ushort8_t;

__device__ __forceinline__ unsigned short f2bf(float f) {
  unsigned u = __float_as_uint(f);
  u += 0x7FFFu + ((u >> 16) & 1u);   // round-to-nearest-even
  return (unsigned short)(u >> 16);
}

// async global->LDS, 16B per lane; LDS dest = wave-uniform base + lane*16
__device__ __forceinline__ void gload_lds16(const unsigned short* g, unsigned short* l) {
  __builtin_amdgcn_global_load_lds(
      (const __attribute__((address_space(1))) unsigned int*)g,
      (__attribute__((address_space(3))) unsigned int*)l, 16, 0, 0);
}

#define MAXC 8

// ---- kernel 1: fused prep (unchanged champion version) ----
__global__ void k_prep(const float* __restrict__ W, unsigned short* __restrict__ Wt,
                       int Dd, int Oo,
                       const float* __restrict__ x, unsigned short* __restrict__ xb, int nX,
                       const int* __restrict__ cid, int* __restrict__ counts,
                       int* __restrict__ bucket, int T, int C, int tpw) {
  int b   = blockIdx.x;
  int tid = threadIdx.x;

  if (b == 0) {
    __shared__ int cnt[256][MAXC];
    int tpt = (T + 255) / 256;
    int t0  = tid * tpt;
    int t1  = min(t0 + tpt, T);
    for (int c = 0; c < C; ++c) cnt[tid][c] = 0;
    for (int t = t0; t < t1; ++t) cnt[tid][cid[t]]++;
    __syncthreads();
    if (tid < C) {
      int run = 0;
      for (int t = 0; t < 256; ++t) { int v = cnt[t][tid]; cnt[t][tid] = run; run += v; }
      counts[tid] = run;
    }
    __syncthreads();
    for (int t = t0; t < t1; ++t) {
      int c = cid[t];
      int p = cnt[tid][c]++;
      bucket[c * T + p] = t;
    }
    return;
  }

  if (b > tpw) {  // cvt role: x fp32 -> bf16, 8/thread
    int i = ((b - tpw - 1) * 256 + tid) * 8;
    if (i >= nX) return;
    float4 a0 = *reinterpret_cast<const float4*>(x + i);
    float4 a1 = *reinterpret_cast<const float4*>(x + i + 4);
    ushort8_t o;
    o[0] = f2bf(a0.x); o[1] = f2bf(a0.y); o[2] = f2bf(a0.z); o[3] = f2bf(a0.w);
    o[4] = f2bf(a1.x); o[5] = f2bf(a1.y); o[6] = f2bf(a1.z); o[7] = f2bf(a1.w);
    *reinterpret_cast<ushort8_t*>(xb + i) = o;
    return;
  }

  // transpose role: 64x64 tile of W[c]
  int bb  = b - 1;
  int tpc = (Dd / 64) * (Oo / 64);
  int c   = bb / tpc;
  int rem = bb % tpc;
  int d0  = (rem / (Oo / 64)) * 64;
  int o0  = (rem % (Oo / 64)) * 64;

  __shared__ float t[64][65];
  const float* Wc = W + (size_t)c * Dd * Oo;
#pragma unroll
  for (int p = 0; p < 4; ++p) {
    int chunk = p * 256 + tid;
    int r  = chunk >> 4;
    int cb = chunk & 15;
    float4 v = *reinterpret_cast<const float4*>(Wc + (size_t)(d0 + r) * Oo + o0 + cb * 4);
    t[r][cb * 4 + 0] = v.x; t[r][cb * 4 + 1] = v.y;
    t[r][cb * 4 + 2] = v.z; t[r][cb * 4 + 3] = v.w;
  }
  __syncthreads();
  unsigned short* Wtc = Wt + (size_t)c * Oo * Dd;
#pragma unroll
  for (int p = 0; p < 2; ++p) {
    int chunk = p * 256 + tid;
    int orow = chunk >> 3;
    int dseg = chunk & 7;
    ushort8_t w;
#pragma unroll
    for (int j = 0; j < 8; ++j) w[j] = f2bf(t[dseg * 8 + j][orow]);
    *reinterpret_cast<ushort8_t*>(Wtc + (size_t)(o0 + orow) * Dd + d0 + dseg * 8) = w;
  }
}

// ---- kernel 2: grouped GEMM, 128x128, 16 waves, phase-split K-step ----
#define BM 128
#define BN 128
#define BK 64
#define TILE_A (BM * BK)   // 8192 elems = 16KB
#define TILE_B (BN * BK)   // 8192 elems = 16KB

__global__ __launch_bounds__(1024) void k_ggemm(
    const unsigned short* __restrict__ xb, const unsigned short* __restrict__ Wt,
    const float* __restrict__ bias, const int* __restrict__ counts,
    const int* __restrict__ bucket, float* __restrict__ out,
    int T, int Dd, int Oo) {
  int c  = blockIdx.x;
  int Mc = counts[c];
  int m0 = blockIdx.z * BM;
  if (m0 >= Mc) return;  // block-uniform exit
  int n0 = blockIdx.y * BN;

  extern __shared__ __align__(16) unsigned short smem[];  // 96KB dynamic
  unsigned short* Al = smem;                 // 3 x TILE_A
  unsigned short* Bl = smem + 3 * TILE_A;    // 3 x TILE_B

  const int tid  = threadIdx.x;
  const int lane = tid & 63;
  const int wid  = tid >> 6;                 // 0..15
  const int wm   = wid >> 2, wn = wid & 3;   // 4x4 waves, each 32x32 of C

  const int* buck = bucket + c * T;
  const unsigned short* Wc = Wt + (size_t)c * Oo * Dd;

  // staging: per wave 1 A-gload + 1 B-gload per tile; wave w covers rows
  // [w*8, w*8+8). Linear LDS dest; global source seg pre-swizzled
  // (seg = (lane&7) ^ (row&7)) so swizzled ds_read sees linear k. [rule 21]
  const unsigned short* aSrc;
  const unsigned short* bSrc;
  int sOff;  // wave-uniform LDS element offset (same for A and B)
  {
    int row = wid * 8 + (lane >> 3);
    int seg = (lane & 7) ^ (row & 7);
    int mr  = m0 + row;
    int tok = buck[mr < Mc ? mr : Mc - 1];  // clamp; masked at epilogue
    aSrc = xb + (size_t)tok * Dd + seg * 8;
    bSrc = Wc + (size_t)(n0 + row) * Dd + seg * 8;
    sOff = (wid * 8) * BK;
  }

  // hoist bias (2 VGPRs) out of the epilogue
  float bias_r[2];
#pragma unroll
  for (int ni = 0; ni < 2; ++ni)
    bias_r[ni] = bias[c * Oo + n0 + wn * 32 + ni * 16 + (lane & 15)];

  const f32x4 fzero = {0.f, 0.f, 0.f, 0.f};
  f32x4 acc[2][2];
#pragma unroll
  for (int i = 0; i < 2; ++i)
#pragma unroll
    for (int j = 0; j < 2; ++j) acc[i][j] = fzero;

  const int KT = Dd / BK;  // 16

  // prologue: issue tiles 0 and 1 (2 gloads each per wave)
#pragma unroll
  for (int t8 = 0; t8 < 2; ++t8) {
    int ko = t8 * BK;
    gload_lds16(aSrc + ko, Al + t8 * TILE_A + sOff);
    gload_lds16(bSrc + ko, Bl + t8 * TILE_B + sOff);
  }

  for (int kt = 0; kt < KT; ++kt) {
    int cur = kt % 3;
    // seam: my prev frag ds_reads drained; tile kt's 2 loads landed
    // (exactly 2 newer in flight: A/B of kt+1... issued last iter)
    asm volatile("s_waitcnt lgkmcnt(0)" ::: "memory");
    if (kt < KT - 1) {
      asm volatile("s_waitcnt vmcnt(2)" ::: "memory");
    } else {
      asm volatile("s_waitcnt vmcnt(0)" ::: "memory");
    }
    __builtin_amdgcn_sched_barrier(0);
    __builtin_amdgcn_s_barrier();
    __builtin_amdgcn_sched_barrier(0);

    int nb = (cur + 2 >= 3) ? cur - 1 : cur + 2;
    // phase 0: issue A(kt+2); frags kk=0; prioritized MFMA
    if (kt + 2 < KT) gload_lds16(aSrc + (kt + 2) * BK, Al + nb * TILE_A + sOff);
    {
      bf16x8 af[2], bf[2];
#pragma unroll
      for (int mi = 0; mi < 2; ++mi) {
        int row  = wm * 32 + mi * 16 + (lane & 15);
        int slot = (lane >> 4) ^ (row & 7);
        af[mi] = *reinterpret_cast<const bf16x8*>(&Al[cur * TILE_A + row * BK + slot * 8]);
      }
#pragma unroll
      for (int ni = 0; ni < 2; ++ni) {
        int row  = wn * 32 + ni * 16 + (lane & 15);
        int slot = (lane >> 4) ^ (row & 7);
        bf[ni] = *reinterpret_cast<const bf16x8*>(&Bl[cur * TILE_B + row * BK + slot * 8]);
      }
      __builtin_amdgcn_s_setprio(1);
#pragma unroll
      for (int mi = 0; mi < 2; ++mi)
#pragma unroll
        for (int ni = 0; ni < 2; ++ni)
          acc[mi][ni] = __builtin_amdgcn_mfma_f32_16x16x32_bf16(af[mi], bf[ni], acc[mi][ni], 0, 0, 0);
      __builtin_amdgcn_s_setprio(0);
    }
    // mid-phase rendezvous: waves interleave phase-0 MFMA with phase-1 staging
    __builtin_amdgcn_sched_barrier(0);
    __builtin_amdgcn_s_barrier();
    __builtin_amdgcn_sched_barrier(0);
    // phase 1: issue B(kt+2); frags kk=1; prioritized MFMA
    if (kt + 2 < KT) gload_lds16(bSrc + (kt + 2) * BK, Bl + nb * TILE_B + sOff);
    {
      bf16x8 af[2], bf[2];
#pragma unroll
      for (int mi = 0; mi < 2; ++mi) {
        int row  = wm * 32 + mi * 16 + (lane & 15);
        int slot = (4 + (lane >> 4)) ^ (row & 7);
        af[mi] = *reinterpret_cast<const bf16x8*>(&Al[cur * TILE_A + row * BK + slot * 8]);
      }
#pragma unroll
      for (int ni = 0; ni < 2; ++ni) {
        int row  = wn * 32 + ni * 16 + (lane & 15);
        int slot = (4 + (lane >> 4)) ^ (row & 7);
        bf[ni] = *reinterpret_cast<const bf16x8*>(&Bl[cur * TILE_B + row * BK + slot * 8]);
      }
      __builtin_amdgcn_s_setprio(1);
#pragma unroll
      for (int mi = 0; mi < 2; ++mi)
#pragma unroll
        for (int ni = 0; ni < 2; ++ni)
          acc[mi][ni] = __builtin_amdgcn_mfma_f32_16x16x32_bf16(af[mi], bf[ni], acc[mi][ni], 0, 0, 0);
      __builtin_amdgcn_s_setprio(0);
    }
  }

  // epilogue: D layout col=lane&15, row=(lane>>4)*4+r  [m89-verified]
#pragma unroll
  for (int mi = 0; mi < 2; ++mi) {
    int rb = m0 + wm * 32 + mi * 16 + (lane >> 4) * 4;
#pragma unroll
    for (int r = 0; r < 4; ++r) {
      int mrow = rb + r;
      if (mrow < Mc) {
        int tok = buck[mrow];
        float* orow = out + (size_t)tok * Oo;
#pragma unroll
        for (int ni = 0; ni < 2; ++ni) {
          int col = n0 + wn * 32 + ni * 16 + (lane & 15);
          orow[col] = acc[mi][ni][r] + bias_r[ni];
        }
      }
    }
  }
}

extern "C" void kernel_launch(void* const* d_in, const int* in_sizes, int n_in,
                              void* d_out, int out_size, void* d_ws, size_t ws_size,
                              hipStream_t stream) {
  const float* x    = (const float*)d_in[0];
  const int*   cid  = (const int*)d_in[1];
  const float* W    = (const float*)d_in[2];
  const float* bias = (const float*)d_in[3];
  float* out = (float*)d_out;

  int T = in_sizes[1];            // 4096
  int D = in_sizes[0] / T;        // 1024
  int O = out_size / T;           // 1024
  int C = in_sizes[3] / O;        // 8

  char* ws = (char*)d_ws;
  int* counts = (int*)ws;                                   // C ints
  int* bucket = (int*)(ws + 64);                            // C*T ints
  unsigned short* xb = (unsigned short*)(ws + 64 + (size_t)C * T * 4);  // T*D bf16
  unsigned short* Wt = xb + (size_t)T * D;                  // C*O*D bf16

  int tpw  = C * (D / 64) * (O / 64);            // 2048 transpose blocks
  int cvtb = (T * D / 8 + 255) / 256;            // 2048 cvt blocks
  k_prep<<<1 + tpw + cvtb, 256, 0, stream>>>(W, Wt, D, O, x, xb, T * D,
                                             cid, counts, bucket, T, C, tpw);
  size_t ldsBytes = (size_t)3 * (TILE_A + TILE_B) * sizeof(unsigned short);  // 96KB
  k_ggemm<<<dim3(C, O / BN, (T + BM - 1) / BM), 1024, ldsBytes, stream>>>(
      xb, Wt, bias, counts, bucket, out, T, D, O);
}

// Round 18
// 47.018 us; speedup vs baseline: 1.9942x; 1.0309x over previous
//
#include <hip/hip_runtime.h>

// CategorySpecificLinear: out[t] = x[t] @ W[cid[t]] + bias[cid[t]]
// Pipeline (2 dispatches):
//   k_prep: block 0 = deterministic bucketize; [1,tpw] = W transpose->bf16;
//           rest = x cvt->bf16.  (champion version, unchanged)
//   k_ggemm: champion R11 grid/tile (BM=BN=128, 1024 thr = 16 waves 4x4,
//     cat->XCD) with BK=128 / KT=8 and depth-2 2-phase sync (issue-early
//     stage, one seam per iter). Halves the dominant fixed per-iteration
//     seam cost at constant staged bytes; 128KB LDS (1 blk/CU unchanged).

typedef __attribute__((ext_vector_type(8))) short bf16x8;
typedef __attribute__((ext_vector_type(4))) float f32x4;
typedef __attribute__((ext_vector_type(8))) unsigned short ushort8_t;

__device__ __forceinline__ unsigned short f2bf(float f) {
  unsigned u = __float_as_uint(f);
  u += 0x7FFFu + ((u >> 16) & 1u);   // round-to-nearest-even
  return (unsigned short)(u >> 16);
}

// async global->LDS, 16B per lane; LDS dest = wave-uniform base + lane*16
__device__ __forceinline__ void gload_lds16(const unsigned short* g, unsigned short* l) {
  __builtin_amdgcn_global_load_lds(
      (const __attribute__((address_space(1))) unsigned int*)g,
      (__attribute__((address_space(3))) unsigned int*)l, 16, 0, 0);
}

#define MAXC 8

// ---- kernel 1: fused prep (champion version) ----
__global__ void k_prep(const float* __restrict__ W, unsigned short* __restrict__ Wt,
                       int Dd, int Oo,
                       const float* __restrict__ x, unsigned short* __restrict__ xb, int nX,
                       const int* __restrict__ cid, int* __restrict__ counts,
                       int* __restrict__ bucket, int T, int C, int tpw) {
  int b   = blockIdx.x;
  int tid = threadIdx.x;

  if (b == 0) {
    __shared__ int cnt[256][MAXC];
    int tpt = (T + 255) / 256;
    int t0  = tid * tpt;
    int t1  = min(t0 + tpt, T);
    for (int c = 0; c < C; ++c) cnt[tid][c] = 0;
    for (int t = t0; t < t1; ++t) cnt[tid][cid[t]]++;
    __syncthreads();
    if (tid < C) {
      int run = 0;
      for (int t = 0; t < 256; ++t) { int v = cnt[t][tid]; cnt[t][tid] = run; run += v; }
      counts[tid] = run;
    }
    __syncthreads();
    for (int t = t0; t < t1; ++t) {
      int c = cid[t];
      int p = cnt[tid][c]++;
      bucket[c * T + p] = t;
    }
    return;
  }

  if (b > tpw) {  // cvt role: x fp32 -> bf16, 8/thread
    int i = ((b - tpw - 1) * 256 + tid) * 8;
    if (i >= nX) return;
    float4 a0 = *reinterpret_cast<const float4*>(x + i);
    float4 a1 = *reinterpret_cast<const float4*>(x + i + 4);
    ushort8_t o;
    o[0] = f2bf(a0.x); o[1] = f2bf(a0.y); o[2] = f2bf(a0.z); o[3] = f2bf(a0.w);
    o[4] = f2bf(a1.x); o[5] = f2bf(a1.y); o[6] = f2bf(a1.z); o[7] = f2bf(a1.w);
    *reinterpret_cast<ushort8_t*>(xb + i) = o;
    return;
  }

  // transpose role: 64x64 tile of W[c]
  int bb  = b - 1;
  int tpc = (Dd / 64) * (Oo / 64);
  int c   = bb / tpc;
  int rem = bb % tpc;
  int d0  = (rem / (Oo / 64)) * 64;
  int o0  = (rem % (Oo / 64)) * 64;

  __shared__ float t[64][65];
  const float* Wc = W + (size_t)c * Dd * Oo;
#pragma unroll
  for (int p = 0; p < 4; ++p) {
    int chunk = p * 256 + tid;
    int r  = chunk >> 4;
    int cb = chunk & 15;
    float4 v = *reinterpret_cast<const float4*>(Wc + (size_t)(d0 + r) * Oo + o0 + cb * 4);
    t[r][cb * 4 + 0] = v.x; t[r][cb * 4 + 1] = v.y;
    t[r][cb * 4 + 2] = v.z; t[r][cb * 4 + 3] = v.w;
  }
  __syncthreads();
  unsigned short* Wtc = Wt + (size_t)c * Oo * Dd;
#pragma unroll
  for (int p = 0; p < 2; ++p) {
    int chunk = p * 256 + tid;
    int orow = chunk >> 3;
    int dseg = chunk & 7;
    ushort8_t w;
#pragma unroll
    for (int j = 0; j < 8; ++j) w[j] = f2bf(t[dseg * 8 + j][orow]);
    *reinterpret_cast<ushort8_t*>(Wtc + (size_t)(o0 + orow) * Dd + d0 + dseg * 8) = w;
  }
}

// ---- kernel 2: grouped GEMM, 128x128 tile, BK=128, depth-2 2-phase ----
#define BM 128
#define BN 128
#define BK 128
#define TILE_A (BM * BK)   // 16384 elems = 32KB
#define TILE_B (BN * BK)   // 16384 elems = 32KB

__global__ __launch_bounds__(1024) void k_ggemm(
    const unsigned short* __restrict__ xb, const unsigned short* __restrict__ Wt,
    const float* __restrict__ bias, const int* __restrict__ counts,
    const int* __restrict__ bucket, float* __restrict__ out,
    int T, int Dd, int Oo) {
  int c  = blockIdx.x;
  int Mc = counts[c];
  int m0 = blockIdx.z * BM;
  if (m0 >= Mc) return;  // block-uniform exit
  int n0 = blockIdx.y * BN;

  extern __shared__ __align__(16) unsigned short smem[];  // 128KB dynamic
  unsigned short* Al = smem;                 // 2 x TILE_A
  unsigned short* Bl = smem + 2 * TILE_A;    // 2 x TILE_B

  const int tid  = threadIdx.x;
  const int lane = tid & 63;
  const int wid  = tid >> 6;                 // 0..15
  const int wm   = wid >> 2, wn = wid & 3;   // 4x4 waves, each 32x32 of C

  const int* buck = bucket + c * T;
  const unsigned short* Wc = Wt + (size_t)c * Oo * Dd;

  // staging: per wave 2 A-gloads + 2 B-gloads per tile; gload i covers rows
  // [wid*8 + i*4, +4) (256B rows = 16 x 16B chunks). Linear LDS dest; global
  // source chunk pre-swizzled: seg = (lane&15) ^ (row&15). [rule 21]
  const unsigned short* aSrc[2];
  const unsigned short* bSrc[2];
  int sOff[2];  // wave-uniform LDS element offsets (same for A and B)
#pragma unroll
  for (int i = 0; i < 2; ++i) {
    int row = wid * 8 + i * 4 + (lane >> 4);
    int seg = (lane & 15) ^ (row & 15);
    int mr  = m0 + row;
    int tok = buck[mr < Mc ? mr : Mc - 1];  // clamp; masked at epilogue
    aSrc[i] = xb + (size_t)tok * Dd + seg * 8;
    bSrc[i] = Wc + (size_t)(n0 + row) * Dd + seg * 8;
    sOff[i] = (wid * 8 + i * 4) * BK;
  }

  // hoist bias (2 VGPRs)
  float bias_r[2];
#pragma unroll
  for (int ni = 0; ni < 2; ++ni)
    bias_r[ni] = bias[c * Oo + n0 + wn * 32 + ni * 16 + (lane & 15)];

  const f32x4 fzero = {0.f, 0.f, 0.f, 0.f};
  f32x4 acc[2][2];
#pragma unroll
  for (int i = 0; i < 2; ++i)
#pragma unroll
    for (int j = 0; j < 2; ++j) acc[i][j] = fzero;

  const int KT = Dd / BK;  // 8

  // prologue: stage tile 0 into buf 0; drain; barrier
#pragma unroll
  for (int i = 0; i < 2; ++i) {
    gload_lds16(aSrc[i], Al + sOff[i]);
    gload_lds16(bSrc[i], Bl + sOff[i]);
  }
  asm volatile("s_waitcnt vmcnt(0)" ::: "memory");
  __builtin_amdgcn_sched_barrier(0);
  __builtin_amdgcn_s_barrier();

  for (int kt = 0; kt < KT; ++kt) {
    int cur = kt & 1;
    // issue tile kt+1 into the other buffer FIRST (latency hides under compute);
    // its readers (iter kt-1) drained at the previous seam.
    if (kt + 1 < KT) {
      int ko = (kt + 1) * BK;
      int nb = cur ^ 1;
#pragma unroll
      for (int i = 0; i < 2; ++i) {
        gload_lds16(aSrc[i] + ko, Al + nb * TILE_A + sOff[i]);
        gload_lds16(bSrc[i] + ko, Bl + nb * TILE_B + sOff[i]);
      }
    }
    // compute tile kt: 4 kk-slabs x 4 MFMA (16 MFMA/wave/iter)
#pragma unroll
    for (int kk = 0; kk < 4; ++kk) {
      bf16x8 af[2], bf[2];
#pragma unroll
      for (int mi = 0; mi < 2; ++mi) {
        int row  = wm * 32 + mi * 16 + (lane & 15);
        int slot = (kk * 4 + (lane >> 4)) ^ (row & 15);
        af[mi] = *reinterpret_cast<const bf16x8*>(&Al[cur * TILE_A + row * BK + slot * 8]);
      }
#pragma unroll
      for (int ni = 0; ni < 2; ++ni) {
        int row  = wn * 32 + ni * 16 + (lane & 15);
        int slot = (kk * 4 + (lane >> 4)) ^ (row & 15);
        bf[ni] = *reinterpret_cast<const bf16x8*>(&Bl[cur * TILE_B + row * BK + slot * 8]);
      }
#pragma unroll
      for (int mi = 0; mi < 2; ++mi)
#pragma unroll
        for (int ni = 0; ni < 2; ++ni)
          acc[mi][ni] = __builtin_amdgcn_mfma_f32_16x16x32_bf16(af[mi], bf[ni], acc[mi][ni], 0, 0, 0);
    }
    // seam: my frag ds_reads done; next tile's loads landed; all waves rendezvous
    if (kt + 1 < KT) {
      asm volatile("s_waitcnt lgkmcnt(0)" ::: "memory");
      asm volatile("s_waitcnt vmcnt(0)" ::: "memory");
      __builtin_amdgcn_sched_barrier(0);
      __builtin_amdgcn_s_barrier();
      __builtin_amdgcn_sched_barrier(0);
    }
  }

  // epilogue: D layout col=lane&15, row=(lane>>4)*4+r  [m89-verified]
#pragma unroll
  for (int mi = 0; mi < 2; ++mi) {
    int rb = m0 + wm * 32 + mi * 16 + (lane >> 4) * 4;
#pragma unroll
    for (int r = 0; r < 4; ++r) {
      int mrow = rb + r;
      if (mrow < Mc) {
        int tok = buck[mrow];
        float* orow = out + (size_t)tok * Oo;
#pragma unroll
        for (int ni = 0; ni < 2; ++ni) {
          int col = n0 + wn * 32 + ni * 16 + (lane & 15);
          orow[col] = acc[mi][ni][r] + bias_r[ni];
        }
      }
    }
  }
}

extern "C" void kernel_launch(void* const* d_in, const int* in_sizes, int n_in,
                              void* d_out, int out_size, void* d_ws, size_t ws_size,
                              hipStream_t stream) {
  const float* x    = (const float*)d_in[0];
  const int*   cid  = (const int*)d_in[1];
  const float* W    = (const float*)d_in[2];
  const float* bias = (const float*)d_in[3];
  float* out = (float*)d_out;

  int T = in_sizes[1];            // 4096
  int D = in_sizes[0] / T;        // 1024
  int O = out_size / T;           // 1024
  int C = in_sizes[3] / O;        // 8

  char* ws = (char*)d_ws;
  int* counts = (int*)ws;                                   // C ints
  int* bucket = (int*)(ws + 64);                            // C*T ints
  unsigned short* xb = (unsigned short*)(ws + 64 + (size_t)C * T * 4);  // T*D bf16
  unsigned short* Wt = xb + (size_t)T * D;                  // C*O*D bf16

  int tpw  = C * (D / 64) * (O / 64);            // 2048 transpose blocks
  int cvtb = (T * D / 8 + 255) / 256;            // 2048 cvt blocks
  k_prep<<<1 + tpw + cvtb, 256, 0, stream>>>(W, Wt, D, O, x, xb, T * D,
                                             cid, counts, bucket, T, C, tpw);
  size_t ldsBytes = (size_t)2 * (TILE_A + TILE_B) * sizeof(unsigned short);  // 128KB
  k_ggemm<<<dim3(C, O / BN, (T + BM - 1) / BM), 1024, ldsBytes, stream>>>(
      xb, Wt, bias, counts, bucket, out, T, D, O);
}